// Round 23
// baseline (245.805 us; speedup 1.0000x reference)
//
#include <hip/hip_runtime.h>

typedef _Float16 f16;
typedef _Float16 f16x8 __attribute__((ext_vector_type(8)));
typedef float f32x4 __attribute__((ext_vector_type(4)));

#define MFMA16(a, b, c) __builtin_amdgcn_mfma_f32_16x16x32_f16(a, b, c, 0, 0, 0)

// M=128 per block, 512 threads (8 waves), 512 blocks.
// 144 KiB LDS arena (offsets in bytes):
//   PANa [128][128] f16 @0       (32K) h0 K-panel (even p), stride 256, swizzled
//   PANb [128][128] f16 @32768   (32K) h0 K-panel (odd p)
//   h1A  [128][256] f16 @65536   (64K) L2 N-cols 0..255
//   x    [128][64]  f16 @131072  (16K) staged input, swizzled
//   h1B  [128][256] f16 @0       (64K) L2 N-cols 256..511 (over dead PANs)
//   h2   [128][256] f16 @65536   (64K) (over dead h1A, after L3 reads)
//   log  [128][112] f32 @0       (57K) (over dead h1B)
//   proj [128][104] f32 @65536   (53K) (over dead h2)
#define PANA 0
#define PANB 32768
#define H1A 65536
#define XOFF 131072
#define H1B 0
#define H2O 65536
#define LGO 0
#define PRO 65536
#define SMEM_BYTES 147456

// ---------------- prep: transpose-cast weights to f16 ----------------
__global__ void k_tr(const float* __restrict__ W, f16* __restrict__ Wt,
                     int K, int N, int lgKp) {
  int t = blockIdx.x * 256 + threadIdx.x;
  int n = t >> lgKp, k = t & ((1 << lgKp) - 1);
  float v = (k < K && n < N) ? W[k * N + n] : 0.f;
  Wt[t] = (f16)v;
}

// ---------------- fused MLP (f16, M=128) + C51 projection ----------------

// 8 row-groups in two halves of 4; A from swizzled LDS, B from global.
template <int KSTEPS, int NT, int SBIN>
__device__ __forceinline__ void layer8(const char* sm, int inOff,
                                       const f16* __restrict__ wt, int ldw,
                                       int nbase, int kbase, int lr, int ls,
                                       f32x4 (&acc)[NT][8]) {
  const int xr = (lr & 7) << 4;
  const char* pb = sm + inOff + lr * SBIN;
  const f16* wb = wt + (size_t)(nbase + lr) * ldw + kbase + ls * 8;
#pragma unroll 2
  for (int ks = 0; ks < KSTEPS; ++ks) {
    int cb = (ks * 64 + ls * 16) ^ xr;
    f16x8 b[NT];
#pragma unroll
    for (int nt = 0; nt < NT; ++nt)
      b[nt] = *(const f16x8*)(wb + nt * 16 * ldw + ks * 32);
#pragma unroll
    for (int mh = 0; mh < 2; ++mh) {
      f16x8 a[4];
#pragma unroll
      for (int q = 0; q < 4; ++q)
        a[q] = *(const f16x8*)(pb + (mh * 4 + q) * 16 * SBIN + cb);
#pragma unroll
      for (int nt = 0; nt < NT; ++nt)
#pragma unroll
        for (int q = 0; q < 4; ++q)
          acc[nt][mh * 4 + q] = MFMA16(a[q], b[nt], acc[nt][mh * 4 + q]);
    }
  }
}

// bias + relu + f16 cast -> swizzled LDS (stride sbout bytes)
template <int NT>
__device__ __forceinline__ void epi8(char* sm, int outOff, int sbout,
                                     const float* __restrict__ bias, int nbias,
                                     int colbase, int lr, int ls,
                                     f32x4 (&acc)[NT][8]) {
#pragma unroll
  for (int nt = 0; nt < NT; ++nt) {
    float bv = bias[nbias + nt * 16 + lr];
    int cb = (colbase + nt * 16 + lr) * 2;
#pragma unroll
    for (int m = 0; m < 8; ++m)
#pragma unroll
      for (int r = 0; r < 4; ++r) {
        int row = m * 16 + ls * 4 + r;
        *(f16*)(sm + outOff + row * sbout + (cb ^ ((row & 7) << 4))) =
            (f16)fmaxf(acc[nt][m][r] + bv, 0.f);
      }
  }
}

__global__ __launch_bounds__(512, 2) void k_fused(
    const float* __restrict__ obs, const float* __restrict__ act,
    const f16* __restrict__ w0t, const f16* __restrict__ w1t,
    const f16* __restrict__ w2t, const f16* __restrict__ w3t,
    const float* __restrict__ b0p, const float* __restrict__ b1p,
    const float* __restrict__ b2p, const float* __restrict__ b3p,
    const float* __restrict__ rew, const float* __restrict__ boot,
    const float* __restrict__ disc, const float* __restrict__ qsup,
    float* __restrict__ out) {
  __shared__ __align__(16) char sm[SMEM_BYTES];
  const int tid = threadIdx.x;
  const int wv = tid >> 6, l = tid & 63;
  const int lr = l & 15, ls = l >> 4;
  const int r0 = blockIdx.x * 128;
  const int xr = (lr & 7) << 4;

  // ---- stage x = concat(obs,act,pad)[128][64] f16 into LDS (swizzled) ----
#pragma unroll
  for (int half = 0; half < 2; ++half) {
    int a = tid + half * 512;          // 1024 slots: row*8+group
    int row = a >> 3, g = a & 7;
    const float* ob = obs + (size_t)(r0 + row) * 48;
    const float* ac = act + (size_t)(r0 + row) * 12;
    float f[8];
    if (g < 6) {
#pragma unroll
      for (int i = 0; i < 8; ++i) f[i] = ob[g * 8 + i];
    } else if (g == 6) {
#pragma unroll
      for (int i = 0; i < 8; ++i) f[i] = ac[i];
    } else {
#pragma unroll
      for (int i = 0; i < 8; ++i) f[i] = (i < 4) ? ac[8 + i] : 0.f;
    }
    f16x8 h;
#pragma unroll
    for (int i = 0; i < 8; ++i) h[i] = (f16)f[i];
    *(f16x8*)(sm + XOFF + row * 128 + ((g * 16) ^ ((row & 7) << 4))) = h;
  }
  __syncthreads();

  // layer-1 panel builder: h0 cols [p*128,(p+1)*128) -> buf (stride 256).
  // Each wave owns 16 cols. x read from LDS (cheap rebuild).
  auto layer1_panel = [&](int p, int bufOff) {
    int n0g = p * 128 + wv * 16;
    const f16* b0 = w0t + (size_t)(n0g + lr) * 64 + ls * 8;
    f16x8 bf0 = *(const f16x8*)(b0);
    f16x8 bf1 = *(const f16x8*)(b0 + 32);
    float bv = b0p[n0g + lr];
    int cb = (wv * 16 + lr) * 2;
#pragma unroll
    for (int m = 0; m < 8; ++m) {
      const char* px = sm + XOFF + (m * 16 + lr) * 128;
      f16x8 a0 = *(const f16x8*)(px + ((ls * 16) ^ xr));
      f16x8 a1 = *(const f16x8*)(px + ((64 + ls * 16) ^ xr));
      f32x4 c = {0.f, 0.f, 0.f, 0.f};
      c = MFMA16(a0, bf0, c);
      c = MFMA16(a1, bf1, c);
#pragma unroll
      for (int r = 0; r < 4; ++r) {
        int row = m * 16 + ls * 4 + r;
        *(f16*)(sm + bufOff + row * 256 + (cb ^ ((row & 7) << 4))) =
            (f16)fmaxf(c[r] + bv, 0.f);
      }
    }
  };

  // ---- layers 1+2: two N-halves of 256; PAN double-buffered pipeline ----
  // Epoch e: build(p+1 -> nxt) overlaps consume(p <- cur). PAN written in
  // epoch e is read in e+1 and rewritten in e+2 (barrier-separated).
  for (int nh = 0; nh < 2; ++nh) {
    f32x4 acc2[2][8];
#pragma unroll
    for (int nt = 0; nt < 2; ++nt)
#pragma unroll
      for (int m = 0; m < 8; ++m) acc2[nt][m] = (f32x4){0.f, 0.f, 0.f, 0.f};

    layer1_panel(0, PANA);
    __syncthreads();
    for (int p = 0; p < 8; ++p) {
      int cur = (p & 1) ? PANB : PANA;
      int nxt = (p & 1) ? PANA : PANB;
      if (p < 7) layer1_panel(p + 1, nxt);  // loads issue under consume MFMAs
      layer8<4, 2, 256>(sm, cur, w1t, 1024, nh * 256 + wv * 32, p * 128,
                        lr, ls, acc2);
      __syncthreads();
    }
    // write this h1 half (local col = wv*32+nt*16+lr, stride 512)
    epi8<2>(sm, nh == 0 ? H1A : H1B, 512, b1p, nh * 256 + wv * 32, wv * 32,
            lr, ls, acc2);
    __syncthreads();
  }

  // ---- layer 3: K=512 via two h1 halves, N=256 ----
  f32x4 acc3[2][8];
#pragma unroll
  for (int nt = 0; nt < 2; ++nt)
#pragma unroll
    for (int m = 0; m < 8; ++m) acc3[nt][m] = (f32x4){0.f, 0.f, 0.f, 0.f};
  layer8<8, 2, 512>(sm, H1A, w2t, 512, wv * 32, 0, lr, ls, acc3);
  layer8<8, 2, 512>(sm, H1B, w2t, 512, wv * 32, 256, lr, ls, acc3);
  __syncthreads();  // all h1 reads done
  epi8<2>(sm, H2O, 512, b2p, wv * 32, wv * 32, lr, ls, acc3);  // over h1A
  __syncthreads();  // h2 complete

  // ---- layer 4: K=256, N=112 (waves 0..6) -> logits f32 @LGO ----
  if (wv < 7) {
    f32x4 acc4[1][8];
#pragma unroll
    for (int m = 0; m < 8; ++m) acc4[0][m] = (f32x4){0.f, 0.f, 0.f, 0.f};
    layer8<8, 1, 512>(sm, H2O, w3t, 256, wv * 16, 0, lr, ls, acc4);
    int col = wv * 16 + lr;
    float bv = (col < 101) ? b3p[col] : 0.f;
    float* Lg = (float*)(sm + LGO);
#pragma unroll
    for (int m = 0; m < 8; ++m)
#pragma unroll
      for (int r = 0; r < 4; ++r) {
        int row = m * 16 + ls * 4 + r;
        Lg[row * 112 + col] = acc4[0][m][r] + bv;
      }
  }
  __syncthreads();  // logits complete; h2 about to die

  // zero projection bins (over dead h2)
  for (int i = tid; i < 128 * 104; i += 512) ((float*)(sm + PRO))[i] = 0.f;
  __syncthreads();

  // ---- softmax (f32) + C51 projection; 4 threads per batch row ----
  {
    int r = tid >> 2, s = tid & 3;
    int rg = r0 + r;
    const float* Lg = (const float*)(sm + LGO);
    float* Pr = (float*)(sm + PRO);
    float lv[26];
    float mx = -3.4e38f;
#pragma unroll
    for (int i = 0; i < 26; ++i) {
      int j = s + 4 * i;
      float x = (j < 101) ? Lg[r * 112 + j] : -3.4e38f;
      lv[i] = x;
      mx = fmaxf(mx, x);
    }
    mx = fmaxf(mx, __shfl_xor(mx, 1));
    mx = fmaxf(mx, __shfl_xor(mx, 2));
    float smv = 0.f;
#pragma unroll
    for (int i = 0; i < 26; ++i) {
      float e = expf(lv[i] - mx);
      lv[i] = e;
      if (s + 4 * i < 101) smv += e;
    }
    smv += __shfl_xor(smv, 1);
    smv += __shfl_xor(smv, 2);

    // Verified-match chain (R8): tz = rew + (boot*disc)*q, clip,
    // b = (tz - V_MIN) * 5.0f   [1/delta_z == 5.0 exactly]
    float rw = rew[rg];
    float bd = __fmul_rn(boot[rg], disc[rg]);
#pragma unroll
    for (int i = 0; i < 26; ++i) {
      int j = s + 4 * i;
      if (j < 101) {
        float p = __fdiv_rn(lv[i], smv);
        float tz = __fadd_rn(rw, __fmul_rn(bd, qsup[j]));
        tz = fminf(fmaxf(tz, -10.f), 10.f);
        float bb = __fmul_rn(__fsub_rn(tz, -10.f), 5.0f);
        float fl = floorf(bb), cu = ceilf(bb);
        int li = (int)fl, ui = (int)cu;
        int l2 = li, u2 = ui;
        if (li == ui) {
          if (ui > 0) l2 = li - 1;
          if (li < 100) u2 = ui + 1;
        }
        atomicAdd(&Pr[r * 104 + l2], __fmul_rn(p, __fsub_rn((float)u2, bb)));
        atomicAdd(&Pr[r * 104 + u2], __fmul_rn(p, __fsub_rn(bb, (float)l2)));
      }
    }
  }
  __syncthreads();

  for (int i = tid; i < 128 * 101; i += 512) {
    int r = i / 101, j = i - r * 101;
    out[(size_t)(r0 + r) * 101 + j] = ((const float*)(sm + PRO))[r * 104 + j];
  }
}

// ---------------- launch ----------------

extern "C" void kernel_launch(void* const* d_in, const int* in_sizes, int n_in,
                              void* d_out, int out_size, void* d_ws, size_t ws_size,
                              hipStream_t stream) {
  const float* obs  = (const float*)d_in[0];
  const float* act  = (const float*)d_in[1];
  const float* rew  = (const float*)d_in[2];
  const float* boot = (const float*)d_in[3];
  const float* disc = (const float*)d_in[4];
  const float* qsup = (const float*)d_in[5];
  const float* W0 = (const float*)d_in[6];  const float* b0 = (const float*)d_in[7];
  const float* W1 = (const float*)d_in[8];  const float* b1 = (const float*)d_in[9];
  const float* W2 = (const float*)d_in[10]; const float* b2 = (const float*)d_in[11];
  const float* W3 = (const float*)d_in[12]; const float* b3 = (const float*)d_in[13];

  char* ws = (char*)d_ws;
  f16* w0t = (f16*)(ws);             // [1024][64]  131072 B
  f16* w1t = (f16*)(ws + 131072);    // [512][1024] 1048576 B
  f16* w2t = (f16*)(ws + 1179648);   // [256][512]  262144 B
  f16* w3t = (f16*)(ws + 1441792);   // [112][256]  57344 B  (end 1499136)

  k_tr<<<256, 256, 0, stream>>>(W0, w0t, 60, 1024, 6);
  k_tr<<<2048, 256, 0, stream>>>(W1, w1t, 1024, 512, 10);
  k_tr<<<512, 256, 0, stream>>>(W2, w2t, 512, 256, 9);
  k_tr<<<112, 256, 0, stream>>>(W3, w3t, 256, 101, 8);

  k_fused<<<512, 512, 0, stream>>>(obs, act, w0t, w1t, w2t, w3t,
                                   b0, b1, b2, b3,
                                   rew, boot, disc, qsup, (float*)d_out);
}

// Round 24
// 232.095 us; speedup vs baseline: 1.0591x; 1.0591x over previous
//
#include <hip/hip_runtime.h>

typedef _Float16 f16;
typedef _Float16 f16x4 __attribute__((ext_vector_type(4)));
typedef _Float16 f16x8 __attribute__((ext_vector_type(8)));
typedef float f32x4 __attribute__((ext_vector_type(4)));
typedef float float4v __attribute__((ext_vector_type(4)));

// swapped-operand MFMA: D = Wfrag * Xfrag -> lane holds 4 consecutive n
#define MFMA16(a, b, c) __builtin_amdgcn_mfma_f32_16x16x32_f16(a, b, c, 0, 0, 0)

// M=128 per block, 512 threads (8 waves), 512 blocks.  (R22 layout)
#define PAN 0
#define H1A 65536
#define XOFF 131072
#define H1B 0
#define H2O 65536
#define LGO 0
#define PRO 65536
#define SMEM_BYTES 147456

// ---------------- prep: transpose-cast weights to f16 ----------------
__global__ void k_tr(const float* __restrict__ W, f16* __restrict__ Wt,
                     int K, int N, int lgKp) {
  int t = blockIdx.x * 256 + threadIdx.x;
  int n = t >> lgKp, k = t & ((1 << lgKp) - 1);
  float v = (k < K && n < N) ? W[k * N + n] : 0.f;
  Wt[t] = (f16)v;
}

// ---------------- fused MLP (f16, M=128) + C51 projection ----------------

// Loads identical to before; MFMA operands swapped (weights as A-operand).
template <int KSTEPS, int NT, int SBIN>
__device__ __forceinline__ void layer8(const char* sm, int inOff,
                                       const f16* __restrict__ wt, int ldw,
                                       int nbase, int kbase, int lr, int ls,
                                       f32x4 (&acc)[NT][8]) {
  const int xr = (lr & 7) << 4;
  const char* pb = sm + inOff + lr * SBIN;
  const f16* wb = wt + (size_t)(nbase + lr) * ldw + kbase + ls * 8;
#pragma unroll 2
  for (int ks = 0; ks < KSTEPS; ++ks) {
    int cb = (ks * 64 + ls * 16) ^ xr;
    f16x8 b[NT];
#pragma unroll
    for (int nt = 0; nt < NT; ++nt)
      b[nt] = *(const f16x8*)(wb + nt * 16 * ldw + ks * 32);
#pragma unroll
    for (int mh = 0; mh < 2; ++mh) {
      f16x8 a[4];
#pragma unroll
      for (int q = 0; q < 4; ++q)
        a[q] = *(const f16x8*)(pb + (mh * 4 + q) * 16 * SBIN + cb);
#pragma unroll
      for (int nt = 0; nt < NT; ++nt)
#pragma unroll
        for (int q = 0; q < 4; ++q)
          acc[nt][mh * 4 + q] = MFMA16(b[nt], a[q], acc[nt][mh * 4 + q]);
    }
  }
}

// Swapped-output epilogue: lane holds n = colbase+nt*16+ls*4+r (r=0..3),
// batch row = m*16+lr  ->  one b64 (f16x4) write per (nt,m); float4 bias.
template <int NT>
__device__ __forceinline__ void epi8(char* sm, int outOff, int sbout,
                                     const float* __restrict__ bias, int nbias,
                                     int colbase, int lr, int ls,
                                     f32x4 (&acc)[NT][8]) {
  const int xr = (lr & 7) << 4;
#pragma unroll
  for (int nt = 0; nt < NT; ++nt) {
    int n0 = nt * 16 + ls * 4;
    float4v b4 = *(const float4v*)(bias + nbias + n0);
    int cb = ((colbase + n0) * 2) ^ xr;
#pragma unroll
    for (int m = 0; m < 8; ++m) {
      f16x4 h;
#pragma unroll
      for (int r = 0; r < 4; ++r)
        h[r] = (f16)fmaxf(acc[nt][m][r] + b4[r], 0.f);
      *(f16x4*)(sm + outOff + (m * 16 + lr) * sbout + cb) = h;
    }
  }
}

__global__ __launch_bounds__(512, 2) void k_fused(
    const float* __restrict__ obs, const float* __restrict__ act,
    const f16* __restrict__ w0t, const f16* __restrict__ w1t,
    const f16* __restrict__ w2t, const f16* __restrict__ w3t,
    const float* __restrict__ b0p, const float* __restrict__ b1p,
    const float* __restrict__ b2p, const float* __restrict__ b3p,
    const float* __restrict__ rew, const float* __restrict__ boot,
    const float* __restrict__ disc, const float* __restrict__ qsup,
    float* __restrict__ out) {
  __shared__ __align__(16) char sm[SMEM_BYTES];
  const int tid = threadIdx.x;
  const int wv = tid >> 6, l = tid & 63;
  const int lr = l & 15, ls = l >> 4;
  const int r0 = blockIdx.x * 128;
  const int xr = (lr & 7) << 4;

  // ---- stage x = concat(obs,act,pad)[128][64] f16 into LDS (swizzled) ----
#pragma unroll
  for (int half = 0; half < 2; ++half) {
    int a = tid + half * 512;
    int row = a >> 3, g = a & 7;
    const float* ob = obs + (size_t)(r0 + row) * 48;
    const float* ac = act + (size_t)(r0 + row) * 12;
    float f[8];
    if (g < 6) {
#pragma unroll
      for (int i = 0; i < 8; ++i) f[i] = ob[g * 8 + i];
    } else if (g == 6) {
#pragma unroll
      for (int i = 0; i < 8; ++i) f[i] = ac[i];
    } else {
#pragma unroll
      for (int i = 0; i < 8; ++i) f[i] = (i < 4) ? ac[8 + i] : 0.f;
    }
    f16x8 h;
#pragma unroll
    for (int i = 0; i < 8; ++i) h[i] = (f16)f[i];
    *(f16x8*)(sm + XOFF + row * 128 + ((g * 16) ^ ((row & 7) << 4))) = h;
  }
  __syncthreads();

  // layer-1 panel builder: h0 cols [p*256,(p+1)*256) -> PAN (stride 512).
  // Each wave owns 32 cols (2 nt). Swapped operands + b64 writes.
  auto layer1_panel = [&](int p) {
#pragma unroll
    for (int nt = 0; nt < 2; ++nt) {
      int n0g = p * 256 + wv * 32 + nt * 16;
      const f16* b0 = w0t + (size_t)(n0g + lr) * 64 + ls * 8;
      f16x8 bf0 = *(const f16x8*)(b0);
      f16x8 bf1 = *(const f16x8*)(b0 + 32);
      float4v b4 = *(const float4v*)(b0p + p * 256 + wv * 32 + nt * 16 + ls * 4);
      int cb = ((wv * 32 + nt * 16 + ls * 4) * 2) ^ xr;
#pragma unroll
      for (int m = 0; m < 8; ++m) {
        const char* px = sm + XOFF + (m * 16 + lr) * 128;
        f16x8 a0 = *(const f16x8*)(px + ((ls * 16) ^ xr));
        f16x8 a1 = *(const f16x8*)(px + ((64 + ls * 16) ^ xr));
        f32x4 c = {0.f, 0.f, 0.f, 0.f};
        c = MFMA16(bf0, a0, c);
        c = MFMA16(bf1, a1, c);
        f16x4 h;
#pragma unroll
        for (int r = 0; r < 4; ++r) h[r] = (f16)fmaxf(c[r] + b4[r], 0.f);
        *(f16x4*)(sm + PAN + (m * 16 + lr) * 512 + cb) = h;
      }
    }
  };

  // ---- layers 1+2: two N-halves of 256, each over 4 K-panels ----
  for (int nh = 0; nh < 2; ++nh) {
    f32x4 acc2[2][8];
#pragma unroll
    for (int nt = 0; nt < 2; ++nt)
#pragma unroll
      for (int m = 0; m < 8; ++m) acc2[nt][m] = (f32x4){0.f, 0.f, 0.f, 0.f};

    for (int p = 0; p < 4; ++p) {
      layer1_panel(p);
      __syncthreads();
      layer8<8, 2, 512>(sm, PAN, w1t, 1024, nh * 256 + wv * 32, p * 256,
                        lr, ls, acc2);
      __syncthreads();
    }
    epi8<2>(sm, nh == 0 ? H1A : H1B, 512, b1p, nh * 256 + wv * 32, wv * 32,
            lr, ls, acc2);
    __syncthreads();
  }

  // ---- layer 3: K=512 via two h1 halves, N=256 ----
  f32x4 acc3[2][8];
#pragma unroll
  for (int nt = 0; nt < 2; ++nt)
#pragma unroll
    for (int m = 0; m < 8; ++m) acc3[nt][m] = (f32x4){0.f, 0.f, 0.f, 0.f};
  layer8<8, 2, 512>(sm, H1A, w2t, 512, wv * 32, 0, lr, ls, acc3);
  layer8<8, 2, 512>(sm, H1B, w2t, 512, wv * 32, 256, lr, ls, acc3);
  __syncthreads();
  epi8<2>(sm, H2O, 512, b2p, wv * 32, wv * 32, lr, ls, acc3);
  __syncthreads();

  // ---- layer 4: K=256, N=112 (waves 0..6) -> logits f32 @LGO ----
  if (wv < 7) {
    f32x4 acc4[1][8];
#pragma unroll
    for (int m = 0; m < 8; ++m) acc4[0][m] = (f32x4){0.f, 0.f, 0.f, 0.f};
    layer8<8, 1, 512>(sm, H2O, w3t, 256, wv * 16, 0, lr, ls, acc4);
    int n0 = wv * 16 + ls * 4;  // 4 consecutive logit cols per lane
    float bv[4];
#pragma unroll
    for (int r = 0; r < 4; ++r) bv[r] = (n0 + r < 101) ? b3p[n0 + r] : 0.f;
    float* Lg = (float*)(sm + LGO);
#pragma unroll
    for (int m = 0; m < 8; ++m) {
      int row = m * 16 + lr;
      float4v v;
#pragma unroll
      for (int r = 0; r < 4; ++r) v[r] = acc4[0][m][r] + bv[r];
      *(float4v*)(Lg + row * 112 + n0) = v;
    }
  }
  __syncthreads();

  // zero projection bins (over dead h2), float4
  for (int i = tid; i < 128 * 104 / 4; i += 512)
    ((float4v*)(sm + PRO))[i] = (float4v){0.f, 0.f, 0.f, 0.f};
  __syncthreads();

  // ---- softmax (f32) + C51 projection; 4 threads per batch row ----
  {
    int r = tid >> 2, s = tid & 3;
    int rg = r0 + r;
    const float* Lg = (const float*)(sm + LGO);
    float* Pr = (float*)(sm + PRO);
    float lv[26];
    float mx = -3.4e38f;
#pragma unroll
    for (int i = 0; i < 26; ++i) {
      int j = s + 4 * i;
      float x = (j < 101) ? Lg[r * 112 + j] : -3.4e38f;
      lv[i] = x;
      mx = fmaxf(mx, x);
    }
    mx = fmaxf(mx, __shfl_xor(mx, 1));
    mx = fmaxf(mx, __shfl_xor(mx, 2));
    float smv = 0.f;
#pragma unroll
    for (int i = 0; i < 26; ++i) {
      float e = expf(lv[i] - mx);
      lv[i] = e;
      if (s + 4 * i < 101) smv += e;
    }
    smv += __shfl_xor(smv, 1);
    smv += __shfl_xor(smv, 2);

    // Verified-match chain (R8): tz = rew + (boot*disc)*q, clip,
    // b = (tz - V_MIN) * 5.0f   [1/delta_z == 5.0 exactly]
    float rw = rew[rg];
    float bd = __fmul_rn(boot[rg], disc[rg]);
#pragma unroll
    for (int i = 0; i < 26; ++i) {
      int j = s + 4 * i;
      if (j < 101) {
        float p = __fdiv_rn(lv[i], smv);
        float tz = __fadd_rn(rw, __fmul_rn(bd, qsup[j]));
        tz = fminf(fmaxf(tz, -10.f), 10.f);
        float bb = __fmul_rn(__fsub_rn(tz, -10.f), 5.0f);
        float fl = floorf(bb), cu = ceilf(bb);
        int li = (int)fl, ui = (int)cu;
        int l2 = li, u2 = ui;
        if (li == ui) {
          if (ui > 0) l2 = li - 1;
          if (li < 100) u2 = ui + 1;
        }
        atomicAdd(&Pr[r * 104 + l2], __fmul_rn(p, __fsub_rn((float)u2, bb)));
        atomicAdd(&Pr[r * 104 + u2], __fmul_rn(p, __fsub_rn(bb, (float)l2)));
      }
    }
  }
  __syncthreads();

  for (int i = tid; i < 128 * 101; i += 512) {
    int r = i / 101, j = i - r * 101;
    out[(size_t)(r0 + r) * 101 + j] = ((const float*)(sm + PRO))[r * 104 + j];
  }
}

// ---------------- launch ----------------

extern "C" void kernel_launch(void* const* d_in, const int* in_sizes, int n_in,
                              void* d_out, int out_size, void* d_ws, size_t ws_size,
                              hipStream_t stream) {
  const float* obs  = (const float*)d_in[0];
  const float* act  = (const float*)d_in[1];
  const float* rew  = (const float*)d_in[2];
  const float* boot = (const float*)d_in[3];
  const float* disc = (const float*)d_in[4];
  const float* qsup = (const float*)d_in[5];
  const float* W0 = (const float*)d_in[6];  const float* b0 = (const float*)d_in[7];
  const float* W1 = (const float*)d_in[8];  const float* b1 = (const float*)d_in[9];
  const float* W2 = (const float*)d_in[10]; const float* b2 = (const float*)d_in[11];
  const float* W3 = (const float*)d_in[12]; const float* b3 = (const float*)d_in[13];

  char* ws = (char*)d_ws;
  f16* w0t = (f16*)(ws);             // [1024][64]  131072 B
  f16* w1t = (f16*)(ws + 131072);    // [512][1024] 1048576 B
  f16* w2t = (f16*)(ws + 1179648);   // [256][512]  262144 B
  f16* w3t = (f16*)(ws + 1441792);   // [112][256]  57344 B  (end 1499136)

  k_tr<<<256, 256, 0, stream>>>(W0, w0t, 60, 1024, 6);
  k_tr<<<2048, 256, 0, stream>>>(W1, w1t, 1024, 512, 10);
  k_tr<<<512, 256, 0, stream>>>(W2, w2t, 512, 256, 9);
  k_tr<<<112, 256, 0, stream>>>(W3, w3t, 256, 101, 8);

  k_fused<<<512, 512, 0, stream>>>(obs, act, w0t, w1t, w2t, w3t,
                                   b0, b1, b2, b3,
                                   rew, boot, disc, qsup, (float*)d_out);
}

// Round 25
// 231.981 us; speedup vs baseline: 1.0596x; 1.0005x over previous
//
#include <hip/hip_runtime.h>

typedef _Float16 f16;
typedef _Float16 f16x4 __attribute__((ext_vector_type(4)));
typedef _Float16 f16x8 __attribute__((ext_vector_type(8)));
typedef float f32x4 __attribute__((ext_vector_type(4)));
typedef float float4v __attribute__((ext_vector_type(4)));

// swapped-operand MFMA: D = Wfrag * Xfrag -> lane holds 4 consecutive n
#define MFMA16(a, b, c) __builtin_amdgcn_mfma_f32_16x16x32_f16(a, b, c, 0, 0, 0)

// M=128 per block, 512 threads (8 waves), 512 blocks.  (R22 layout)
#define PAN 0
#define H1A 65536
#define XOFF 131072
#define H1B 0
#define H2O 65536
#define LGO 0
#define PRO 65536
#define SMEM_BYTES 147456

// ---------------- prep: transpose-cast weights to f16 ----------------
__global__ void k_tr(const float* __restrict__ W, f16* __restrict__ Wt,
                     int K, int N, int lgKp) {
  int t = blockIdx.x * 256 + threadIdx.x;
  int n = t >> lgKp, k = t & ((1 << lgKp) - 1);
  float v = (k < K && n < N) ? W[k * N + n] : 0.f;
  Wt[t] = (f16)v;
}

// ---------------- fused MLP (f16, M=128) + C51 projection ----------------

// FULL unroll: all weight loads of the call visible to the scheduler ->
// deep load pipelining over the ~200cy L2 latency (unroll-2 only covered ~2).
template <int KSTEPS, int NT, int SBIN>
__device__ __forceinline__ void layer8(const char* sm, int inOff,
                                       const f16* __restrict__ wt, int ldw,
                                       int nbase, int kbase, int lr, int ls,
                                       f32x4 (&acc)[NT][8]) {
  const int xr = (lr & 7) << 4;
  const char* pb = sm + inOff + lr * SBIN;
  const f16* wb = wt + (size_t)(nbase + lr) * ldw + kbase + ls * 8;
#pragma unroll
  for (int ks = 0; ks < KSTEPS; ++ks) {
    int cb = (ks * 64 + ls * 16) ^ xr;
    f16x8 b[NT];
#pragma unroll
    for (int nt = 0; nt < NT; ++nt)
      b[nt] = *(const f16x8*)(wb + nt * 16 * ldw + ks * 32);
#pragma unroll
    for (int mh = 0; mh < 2; ++mh) {
      f16x8 a[4];
#pragma unroll
      for (int q = 0; q < 4; ++q)
        a[q] = *(const f16x8*)(pb + (mh * 4 + q) * 16 * SBIN + cb);
#pragma unroll
      for (int nt = 0; nt < NT; ++nt)
#pragma unroll
        for (int q = 0; q < 4; ++q)
          acc[nt][mh * 4 + q] = MFMA16(b[nt], a[q], acc[nt][mh * 4 + q]);
    }
  }
}

// Swapped-output epilogue: lane holds n = colbase+nt*16+ls*4+r (r=0..3),
// batch row = m*16+lr  ->  one b64 (f16x4) write per (nt,m); float4 bias.
template <int NT>
__device__ __forceinline__ void epi8(char* sm, int outOff, int sbout,
                                     const float* __restrict__ bias, int nbias,
                                     int colbase, int lr, int ls,
                                     f32x4 (&acc)[NT][8]) {
  const int xr = (lr & 7) << 4;
#pragma unroll
  for (int nt = 0; nt < NT; ++nt) {
    int n0 = nt * 16 + ls * 4;
    float4v b4 = *(const float4v*)(bias + nbias + n0);
    int cb = ((colbase + n0) * 2) ^ xr;
#pragma unroll
    for (int m = 0; m < 8; ++m) {
      f16x4 h;
#pragma unroll
      for (int r = 0; r < 4; ++r)
        h[r] = (f16)fmaxf(acc[nt][m][r] + b4[r], 0.f);
      *(f16x4*)(sm + outOff + (m * 16 + lr) * sbout + cb) = h;
    }
  }
}

__global__ __launch_bounds__(512, 2) void k_fused(
    const float* __restrict__ obs, const float* __restrict__ act,
    const f16* __restrict__ w0t, const f16* __restrict__ w1t,
    const f16* __restrict__ w2t, const f16* __restrict__ w3t,
    const float* __restrict__ b0p, const float* __restrict__ b1p,
    const float* __restrict__ b2p, const float* __restrict__ b3p,
    const float* __restrict__ rew, const float* __restrict__ boot,
    const float* __restrict__ disc, const float* __restrict__ qsup,
    float* __restrict__ out) {
  __shared__ __align__(16) char sm[SMEM_BYTES];
  const int tid = threadIdx.x;
  const int wv = tid >> 6, l = tid & 63;
  const int lr = l & 15, ls = l >> 4;
  const int r0 = blockIdx.x * 128;
  const int xr = (lr & 7) << 4;

  // ---- stage x = concat(obs,act,pad)[128][64] f16 into LDS (swizzled) ----
#pragma unroll
  for (int half = 0; half < 2; ++half) {
    int a = tid + half * 512;
    int row = a >> 3, g = a & 7;
    const float* ob = obs + (size_t)(r0 + row) * 48;
    const float* ac = act + (size_t)(r0 + row) * 12;
    float f[8];
    if (g < 6) {
#pragma unroll
      for (int i = 0; i < 8; ++i) f[i] = ob[g * 8 + i];
    } else if (g == 6) {
#pragma unroll
      for (int i = 0; i < 8; ++i) f[i] = ac[i];
    } else {
#pragma unroll
      for (int i = 0; i < 8; ++i) f[i] = (i < 4) ? ac[8 + i] : 0.f;
    }
    f16x8 h;
#pragma unroll
    for (int i = 0; i < 8; ++i) h[i] = (f16)f[i];
    *(f16x8*)(sm + XOFF + row * 128 + ((g * 16) ^ ((row & 7) << 4))) = h;
  }
  __syncthreads();

  // layer-1 panel builder: h0 cols [p*256,(p+1)*256) -> PAN (stride 512).
  auto layer1_panel = [&](int p) {
#pragma unroll
    for (int nt = 0; nt < 2; ++nt) {
      int n0g = p * 256 + wv * 32 + nt * 16;
      const f16* b0 = w0t + (size_t)(n0g + lr) * 64 + ls * 8;
      f16x8 bf0 = *(const f16x8*)(b0);
      f16x8 bf1 = *(const f16x8*)(b0 + 32);
      float4v b4 = *(const float4v*)(b0p + p * 256 + wv * 32 + nt * 16 + ls * 4);
      int cb = ((wv * 32 + nt * 16 + ls * 4) * 2) ^ xr;
#pragma unroll
      for (int m = 0; m < 8; ++m) {
        const char* px = sm + XOFF + (m * 16 + lr) * 128;
        f16x8 a0 = *(const f16x8*)(px + ((ls * 16) ^ xr));
        f16x8 a1 = *(const f16x8*)(px + ((64 + ls * 16) ^ xr));
        f32x4 c = {0.f, 0.f, 0.f, 0.f};
        c = MFMA16(bf0, a0, c);
        c = MFMA16(bf1, a1, c);
        f16x4 h;
#pragma unroll
        for (int r = 0; r < 4; ++r) h[r] = (f16)fmaxf(c[r] + b4[r], 0.f);
        *(f16x4*)(sm + PAN + (m * 16 + lr) * 512 + cb) = h;
      }
    }
  };

  // ---- layers 1+2: two N-halves of 256, each over 4 K-panels ----
  for (int nh = 0; nh < 2; ++nh) {
    f32x4 acc2[2][8];
#pragma unroll
    for (int nt = 0; nt < 2; ++nt)
#pragma unroll
      for (int m = 0; m < 8; ++m) acc2[nt][m] = (f32x4){0.f, 0.f, 0.f, 0.f};

    for (int p = 0; p < 4; ++p) {
      layer1_panel(p);
      __syncthreads();
      layer8<8, 2, 512>(sm, PAN, w1t, 1024, nh * 256 + wv * 32, p * 256,
                        lr, ls, acc2);
      __syncthreads();
    }
    epi8<2>(sm, nh == 0 ? H1A : H1B, 512, b1p, nh * 256 + wv * 32, wv * 32,
            lr, ls, acc2);
    __syncthreads();
  }

  // ---- layer 3: K=512 via two h1 halves, N=256 ----
  f32x4 acc3[2][8];
#pragma unroll
  for (int nt = 0; nt < 2; ++nt)
#pragma unroll
    for (int m = 0; m < 8; ++m) acc3[nt][m] = (f32x4){0.f, 0.f, 0.f, 0.f};
  layer8<8, 2, 512>(sm, H1A, w2t, 512, wv * 32, 0, lr, ls, acc3);
  layer8<8, 2, 512>(sm, H1B, w2t, 512, wv * 32, 256, lr, ls, acc3);
  __syncthreads();
  epi8<2>(sm, H2O, 512, b2p, wv * 32, wv * 32, lr, ls, acc3);
  __syncthreads();

  // ---- layer 4: K=256, N=112 (waves 0..6) -> logits f32 @LGO ----
  if (wv < 7) {
    f32x4 acc4[1][8];
#pragma unroll
    for (int m = 0; m < 8; ++m) acc4[0][m] = (f32x4){0.f, 0.f, 0.f, 0.f};
    layer8<8, 1, 512>(sm, H2O, w3t, 256, wv * 16, 0, lr, ls, acc4);
    int n0 = wv * 16 + ls * 4;  // 4 consecutive logit cols per lane
    float bv[4];
#pragma unroll
    for (int r = 0; r < 4; ++r) bv[r] = (n0 + r < 101) ? b3p[n0 + r] : 0.f;
    float* Lg = (float*)(sm + LGO);
#pragma unroll
    for (int m = 0; m < 8; ++m) {
      int row = m * 16 + lr;
      float4v v;
#pragma unroll
      for (int r = 0; r < 4; ++r) v[r] = acc4[0][m][r] + bv[r];
      *(float4v*)(Lg + row * 112 + n0) = v;
    }
  }
  __syncthreads();

  // zero projection bins (over dead h2), float4
  for (int i = tid; i < 128 * 104 / 4; i += 512)
    ((float4v*)(sm + PRO))[i] = (float4v){0.f, 0.f, 0.f, 0.f};
  __syncthreads();

  // ---- softmax (f32) + C51 projection; 4 threads per batch row ----
  {
    int r = tid >> 2, s = tid & 3;
    int rg = r0 + r;
    const float* Lg = (const float*)(sm + LGO);
    float* Pr = (float*)(sm + PRO);
    float lv[26];
    float mx = -3.4e38f;
#pragma unroll
    for (int i = 0; i < 26; ++i) {
      int j = s + 4 * i;
      float x = (j < 101) ? Lg[r * 112 + j] : -3.4e38f;
      lv[i] = x;
      mx = fmaxf(mx, x);
    }
    mx = fmaxf(mx, __shfl_xor(mx, 1));
    mx = fmaxf(mx, __shfl_xor(mx, 2));
    float smv = 0.f;
#pragma unroll
    for (int i = 0; i < 26; ++i) {
      float e = expf(lv[i] - mx);
      lv[i] = e;
      if (s + 4 * i < 101) smv += e;
    }
    smv += __shfl_xor(smv, 1);
    smv += __shfl_xor(smv, 2);

    // Verified-match chain (R8): tz = rew + (boot*disc)*q, clip,
    // b = (tz - V_MIN) * 5.0f   [1/delta_z == 5.0 exactly]
    float rw = rew[rg];
    float bd = __fmul_rn(boot[rg], disc[rg]);
#pragma unroll
    for (int i = 0; i < 26; ++i) {
      int j = s + 4 * i;
      if (j < 101) {
        float p = __fdiv_rn(lv[i], smv);
        float tz = __fadd_rn(rw, __fmul_rn(bd, qsup[j]));
        tz = fminf(fmaxf(tz, -10.f), 10.f);
        float bb = __fmul_rn(__fsub_rn(tz, -10.f), 5.0f);
        float fl = floorf(bb), cu = ceilf(bb);
        int li = (int)fl, ui = (int)cu;
        int l2 = li, u2 = ui;
        if (li == ui) {
          if (ui > 0) l2 = li - 1;
          if (li < 100) u2 = ui + 1;
        }
        atomicAdd(&Pr[r * 104 + l2], __fmul_rn(p, __fsub_rn((float)u2, bb)));
        atomicAdd(&Pr[r * 104 + u2], __fmul_rn(p, __fsub_rn(bb, (float)l2)));
      }
    }
  }
  __syncthreads();

  for (int i = tid; i < 128 * 101; i += 512) {
    int r = i / 101, j = i - r * 101;
    out[(size_t)(r0 + r) * 101 + j] = ((const float*)(sm + PRO))[r * 104 + j];
  }
}

// ---------------- launch ----------------

extern "C" void kernel_launch(void* const* d_in, const int* in_sizes, int n_in,
                              void* d_out, int out_size, void* d_ws, size_t ws_size,
                              hipStream_t stream) {
  const float* obs  = (const float*)d_in[0];
  const float* act  = (const float*)d_in[1];
  const float* rew  = (const float*)d_in[2];
  const float* boot = (const float*)d_in[3];
  const float* disc = (const float*)d_in[4];
  const float* qsup = (const float*)d_in[5];
  const float* W0 = (const float*)d_in[6];  const float* b0 = (const float*)d_in[7];
  const float* W1 = (const float*)d_in[8];  const float* b1 = (const float*)d_in[9];
  const float* W2 = (const float*)d_in[10]; const float* b2 = (const float*)d_in[11];
  const float* W3 = (const float*)d_in[12]; const float* b3 = (const float*)d_in[13];

  char* ws = (char*)d_ws;
  f16* w0t = (f16*)(ws);             // [1024][64]  131072 B
  f16* w1t = (f16*)(ws + 131072);    // [512][1024] 1048576 B
  f16* w2t = (f16*)(ws + 1179648);   // [256][512]  262144 B
  f16* w3t = (f16*)(ws + 1441792);   // [112][256]  57344 B  (end 1499136)

  k_tr<<<256, 256, 0, stream>>>(W0, w0t, 60, 1024, 6);
  k_tr<<<2048, 256, 0, stream>>>(W1, w1t, 1024, 512, 10);
  k_tr<<<512, 256, 0, stream>>>(W2, w2t, 512, 256, 9);
  k_tr<<<112, 256, 0, stream>>>(W3, w3t, 256, 101, 8);

  k_fused<<<512, 512, 0, stream>>>(obs, act, w0t, w1t, w2t, w3t,
                                   b0, b1, b2, b3,
                                   rew, boot, disc, qsup, (float*)d_out);
}